// Round 14
// baseline (103.950 us; speedup 1.0000x reference)
//
#include <hip/hip_runtime.h>
#include <hip/hip_bf16.h>
#include <cstdint>
#include <cstddef>

typedef __attribute__((ext_vector_type(4))) float  f32x4;
typedef __attribute__((ext_vector_type(8))) short  short8;

// bf16 RNE via hardware cvt (compiler fuses pairs into v_cvt_pk_bf16_f32)
__device__ __forceinline__ short f2bf(float f) {
  __hip_bfloat16 h = __float2bfloat16(f);
  return *reinterpret_cast<short*>(&h);
}
__device__ __forceinline__ float sigmoidf(float x) {
  return 1.0f / (1.0f + __expf(-x));
}

// ---------------- pool: g[b,c] = mean_s x[b,c,s] -> bf16 --------------------
// 16 rows per 256-thread block: 784 contiguous float4 loads (dense, full
// lines), LDS scratch, deterministic per-row 49-way sums. 8192 blocks.
__global__ __launch_bounds__(256) void pool_kernel(const float* __restrict__ x,
                                                   short* __restrict__ g) {
  __shared__ float sums[784];
  const int tid = threadIdx.x;
  const f32x4* base = (const f32x4*)(x + (size_t)blockIdx.x * (16 * 196));
#pragma unroll
  for (int it = 0; it < 4; ++it) {
    int i = it * 256 + tid;
    if (it < 3 || tid < 16) {
      f32x4 v = base[i];
      sums[i] = v[0] + v[1] + v[2] + v[3];
    }
  }
  __syncthreads();
  if (tid < 16) {
    float s = 0.f;
#pragma unroll
    for (int j = 0; j < 49; ++j) s += sums[tid * 49 + j];
    g[blockIdx.x * 16 + tid] = f2bf(s * (1.0f / 196.0f));
  }
}

// --------- GEMM1 (R11-proven): 1-deep prefetch, 16-wave K-split -------------
template<int N, int K, int WAVES, bool OUT_BF16>
__device__ __forceinline__ void gemm_body(const short* __restrict__ A,
                                          const float* __restrict__ B,
                                          const float* __restrict__ bias,
                                          void* __restrict__ outp,
                                          float* __restrict__ red) {
  constexpr int KW = K / WAVES;    // k-range per wave
  constexpr int NK = KW / 32;      // MFMA k-steps per wave
  constexpr int NT = WAVES * 64;   // threads
  const int n0  = blockIdx.x * 16;
  const int tid = threadIdx.x;
  const int l   = tid & 63;
  const int wv  = tid >> 6;
  const int kw0 = wv * KW;

  const int ko = (l >> 4) * 8;     // k-offset within 32-k step (operand layout)
  const float* Bp = B + (size_t)(n0 + (l & 15)) * K + kw0 + ko;
  const short* Ap = A + (size_t)(l & 15) * K + kw0 + ko;

  f32x4 acc0 = {}, acc1 = {}, acc2 = {}, acc3 = {};

  f32x4 bc0 = *(const f32x4*)(Bp);
  f32x4 bc1 = *(const f32x4*)(Bp + 4);
  short8 ac0 = *(const short8*)(Ap);
  short8 ac1 = *(const short8*)(Ap + 16 * K);
  short8 ac2 = *(const short8*)(Ap + 32 * K);
  short8 ac3 = *(const short8*)(Ap + 48 * K);

  for (int t = 0; t < NK; ++t) {
    f32x4 bn0 = {}, bn1 = {};
    short8 an0 = {}, an1 = {}, an2 = {}, an3 = {};
    if (t + 1 < NK) {
      const float* bp = Bp + (t + 1) * 32;
      const short* ap = Ap + (t + 1) * 32;
      bn0 = *(const f32x4*)(bp);
      bn1 = *(const f32x4*)(bp + 4);
      an0 = *(const short8*)(ap);
      an1 = *(const short8*)(ap + 16 * K);
      an2 = *(const short8*)(ap + 32 * K);
      an3 = *(const short8*)(ap + 48 * K);
    }
    short8 bb;
    bb[0] = f2bf(bc0[0]); bb[1] = f2bf(bc0[1]); bb[2] = f2bf(bc0[2]); bb[3] = f2bf(bc0[3]);
    bb[4] = f2bf(bc1[0]); bb[5] = f2bf(bc1[1]); bb[6] = f2bf(bc1[2]); bb[7] = f2bf(bc1[3]);
    acc0 = __builtin_amdgcn_mfma_f32_16x16x32_bf16(ac0, bb, acc0, 0, 0, 0);
    acc1 = __builtin_amdgcn_mfma_f32_16x16x32_bf16(ac1, bb, acc1, 0, 0, 0);
    acc2 = __builtin_amdgcn_mfma_f32_16x16x32_bf16(ac2, bb, acc2, 0, 0, 0);
    acc3 = __builtin_amdgcn_mfma_f32_16x16x32_bf16(ac3, bb, acc3, 0, 0, 0);
    bc0 = bn0; bc1 = bn1;
    ac0 = an0; ac1 = an1; ac2 = an2; ac3 = an3;
  }

  // wave-partial -> LDS (C/D layout: m = mi*16 + (l>>4)*4 + r, n = l&15)
  {
    float* rw = red + wv * 1024;
    const int mb = (l >> 4) << 2;
    const int nn = l & 15;
#pragma unroll
    for (int r = 0; r < 4; ++r) rw[(0  + mb + r) * 16 + nn] = acc0[r];
#pragma unroll
    for (int r = 0; r < 4; ++r) rw[(16 + mb + r) * 16 + nn] = acc1[r];
#pragma unroll
    for (int r = 0; r < 4; ++r) rw[(32 + mb + r) * 16 + nn] = acc2[r];
#pragma unroll
    for (int r = 0; r < 4; ++r) rw[(48 + mb + r) * 16 + nn] = acc3[r];
  }
  __syncthreads();

#pragma unroll
  for (int i = tid; i < 1024; i += NT) {
    float s = 0.f;
#pragma unroll
    for (int w = 0; w < WAVES; ++w) s += red[w * 1024 + i];
    int m  = i >> 4;
    int nn = n0 + (i & 15);
    s = sigmoidf(s + bias[nn]);
    if constexpr (OUT_BF16) ((short*)outp)[(size_t)m * N + nn] = f2bf(s);
    else                    ((float*)outp)[(size_t)m * N + nn] = s;
  }
}

// GEMM1: 16 waves (1024 threads), 256 blocks -> 16 waves/CU
__global__ __launch_bounds__(1024, 4) void gemm1_kernel(const short* __restrict__ A,
                                                        const float* __restrict__ B,
                                                        const float* __restrict__ bias,
                                                        short* __restrict__ outp) {
  __shared__ float red[16 * 1024];
  gemm_body<4096, 2048, 16, true>(A, B, bias, outp, red);
}

// --------- GEMM2 partials: 2-way K-split across blocks ----------------------
// grid = 512 n-tiles x 2 k-halves = 1024 blocks -> 4 blocks/CU, 32 waves/CU
// (R12: body fits VGPR=64 -> 8 waves/SIMD; launch_bounds(512,8) pins it).
// Per block: 8 waves split the 2048 k-half (KW=256, NK=8), raw f32 tile out.
__global__ __launch_bounds__(512, 8) void gemm2_part(const short* __restrict__ A,
                                                     const float* __restrict__ B,
                                                     float* __restrict__ part) {
  constexpr int N = 8192, K = 4096, KW = 256, NK = 8;
  __shared__ float red[8 * 1024];
  const int nt = blockIdx.x & 511;
  const int ks = blockIdx.x >> 9;
  const int n0 = nt * 16;
  const int tid = threadIdx.x;
  const int l   = tid & 63;
  const int wv  = tid >> 6;
  const int kw0 = ks * 2048 + wv * KW;

  const int ko = (l >> 4) * 8;
  const float* Bp = B + (size_t)(n0 + (l & 15)) * K + kw0 + ko;
  const short* Ap = A + (size_t)(l & 15) * K + kw0 + ko;

  f32x4 acc0 = {}, acc1 = {}, acc2 = {}, acc3 = {};

  f32x4 bc0 = *(const f32x4*)(Bp);
  f32x4 bc1 = *(const f32x4*)(Bp + 4);
  short8 ac0 = *(const short8*)(Ap);
  short8 ac1 = *(const short8*)(Ap + 16 * K);
  short8 ac2 = *(const short8*)(Ap + 32 * K);
  short8 ac3 = *(const short8*)(Ap + 48 * K);

  for (int t = 0; t < NK; ++t) {
    f32x4 bn0 = {}, bn1 = {};
    short8 an0 = {}, an1 = {}, an2 = {}, an3 = {};
    if (t + 1 < NK) {
      const float* bp = Bp + (t + 1) * 32;
      const short* ap = Ap + (t + 1) * 32;
      bn0 = *(const f32x4*)(bp);
      bn1 = *(const f32x4*)(bp + 4);
      an0 = *(const short8*)(ap);
      an1 = *(const short8*)(ap + 16 * K);
      an2 = *(const short8*)(ap + 32 * K);
      an3 = *(const short8*)(ap + 48 * K);
    }
    short8 bb;
    bb[0] = f2bf(bc0[0]); bb[1] = f2bf(bc0[1]); bb[2] = f2bf(bc0[2]); bb[3] = f2bf(bc0[3]);
    bb[4] = f2bf(bc1[0]); bb[5] = f2bf(bc1[1]); bb[6] = f2bf(bc1[2]); bb[7] = f2bf(bc1[3]);
    acc0 = __builtin_amdgcn_mfma_f32_16x16x32_bf16(ac0, bb, acc0, 0, 0, 0);
    acc1 = __builtin_amdgcn_mfma_f32_16x16x32_bf16(ac1, bb, acc1, 0, 0, 0);
    acc2 = __builtin_amdgcn_mfma_f32_16x16x32_bf16(ac2, bb, acc2, 0, 0, 0);
    acc3 = __builtin_amdgcn_mfma_f32_16x16x32_bf16(ac3, bb, acc3, 0, 0, 0);
    bc0 = bn0; bc1 = bn1;
    ac0 = an0; ac1 = an1; ac2 = an2; ac3 = an3;
  }

  {
    float* rw = red + wv * 1024;
    const int mb = (l >> 4) << 2;
    const int nn = l & 15;
#pragma unroll
    for (int r = 0; r < 4; ++r) rw[(0  + mb + r) * 16 + nn] = acc0[r];
#pragma unroll
    for (int r = 0; r < 4; ++r) rw[(16 + mb + r) * 16 + nn] = acc1[r];
#pragma unroll
    for (int r = 0; r < 4; ++r) rw[(32 + mb + r) * 16 + nn] = acc2[r];
#pragma unroll
    for (int r = 0; r < 4; ++r) rw[(48 + mb + r) * 16 + nn] = acc3[r];
  }
  __syncthreads();

  // reduce 8 wave-partials, write raw f32 partial tile
  float* pp = part + (size_t)ks * (64 * N);
#pragma unroll
  for (int i = tid; i < 1024; i += 512) {
    float s = 0.f;
#pragma unroll
    for (int w = 0; w < 8; ++w) s += red[w * 1024 + i];
    pp[(size_t)(i >> 4) * N + n0 + (i & 15)] = s;
  }
}

// --------- GEMM2 reduce: sum 2 k-half partials + bias + sigmoid -------------
// Also zeroes feat for einsum's atomics. 1024 blocks x 512 threads.
__global__ __launch_bounds__(512) void gemm2_reduce(const float* __restrict__ part,
                                                    const float* __restrict__ bias,
                                                    float* __restrict__ wout,
                                                    float* __restrict__ feat) {
  const int i = blockIdx.x * 512 + threadIdx.x;   // 0..524287 exact
  float s = part[i] + part[524288 + i] + bias[i & 8191];
  wout[i] = sigmoidf(s);
  if (i < 50176) feat[i] = 0.f;
}

// --------- einsum: feat[b,p,s] += (1/C) sum_{c in chunk} w[b,p,c] x[b,c,s] --
// grid = 64 b x 16 c-chunks. Gate values read at loop-uniform addresses ->
// scalar (SGPR) loads; inner loop = 1 vector load + 4 v_fmac(v,s,v).
// feat pre-zeroed by gemm2_reduce; 16-way atomicAdd per element.
__global__ __launch_bounds__(256) void einsum_kernel(const float* __restrict__ x,
                                                     const float* __restrict__ wg,
                                                     float* __restrict__ feat) {
  const int b   = blockIdx.x >> 4;
  const int cc  = blockIdx.x & 15;
  const int tid = threadIdx.x;
  if (tid >= 196) return;
  const float* wp = wg + (size_t)b * 8192 + cc * 128;       // + p*2048 + c (uniform)
  const float* xp = x + (size_t)b * 2048 * 196 + (size_t)cc * 128 * 196 + tid;
  float a0 = 0.f, a1 = 0.f, a2 = 0.f, a3 = 0.f;
#pragma unroll 8
  for (int c = 0; c < 128; ++c) {
    float xv = xp[(size_t)c * 196];
    a0 = __builtin_fmaf(wp[c],        xv, a0);
    a1 = __builtin_fmaf(wp[2048 + c], xv, a1);
    a2 = __builtin_fmaf(wp[4096 + c], xv, a2);
    a3 = __builtin_fmaf(wp[6144 + c], xv, a3);
  }
  const float invC = 1.0f / 2048.0f;
  atomicAdd(feat + (b * 4 + 0) * 196 + tid, a0 * invC);
  atomicAdd(feat + (b * 4 + 1) * 196 + tid, a1 * invC);
  atomicAdd(feat + (b * 4 + 2) * 196 + tid, a2 * invC);
  atomicAdd(feat + (b * 4 + 3) * 196 + tid, a3 * invC);
}

extern "C" void kernel_launch(void* const* d_in, const int* in_sizes, int n_in,
                              void* d_out, int out_size, void* d_ws, size_t ws_size,
                              hipStream_t stream) {
  const float* x  = (const float*)d_in[0];   // [64,2048,14,14]
  const float* w1 = (const float*)d_in[1];   // [4096,2048]
  const float* b1 = (const float*)d_in[2];   // [4096]
  const float* w2 = (const float*)d_in[3];   // [8192,4096]
  const float* b2 = (const float*)d_in[4];   // [8192]
  float* out = (float*)d_out;

  short* g_bf = (short*)d_ws;                        // 64*2048 bf16 (256 KB)
  short* h_bf = g_bf + 64 * 2048;                    // 64*4096 bf16 (512 KB)
  float* part = (float*)((char*)d_ws + (1 << 20));   // 2 x 64*8192 f32 (4 MB)

  float* wout = out;                         // [64, 8192] == [B,P,C] flat
  float* feat = out + 524288;                // [64, 4, 196]

  // 1) pool -> g (bf16): 8192 blocks x 16 rows
  pool_kernel<<<8192, 256, 0, stream>>>(x, g_bf);

  // 2) GEMM1: h = sigmoid(g @ w1^T + b1), bf16 out (256 blocks x 16 waves)
  gemm1_kernel<<<4096 / 16, 1024, 0, stream>>>(g_bf, w1, b1, h_bf);

  // 3) GEMM2 partials: 512 n-tiles x 2 k-halves -> 4 blocks/CU, 32 waves/CU
  gemm2_part<<<1024, 512, 0, stream>>>(h_bf, w2, part);

  // 4) reduce + bias + sigmoid -> wout; zero feat
  gemm2_reduce<<<1024, 512, 0, stream>>>(part, b2, wout, feat);

  // 5) einsum -> feat (atomic accumulate over 16 c-chunks)
  einsum_kernel<<<64 * 16, 256, 0, stream>>>(x, wout, feat);
}

// Round 15
// 96.373 us; speedup vs baseline: 1.0786x; 1.0786x over previous
//
#include <hip/hip_runtime.h>
#include <hip/hip_bf16.h>
#include <cstdint>
#include <cstddef>

typedef __attribute__((ext_vector_type(4))) float  f32x4;
typedef __attribute__((ext_vector_type(8))) short  short8;

typedef __attribute__((address_space(3))) uint32_t as3_u32;
typedef __attribute__((address_space(1))) uint32_t as1_u32;

// bf16 RNE via hardware cvt (compiler fuses pairs into v_cvt_pk_bf16_f32)
__device__ __forceinline__ short f2bf(float f) {
  __hip_bfloat16 h = __float2bfloat16(f);
  return *reinterpret_cast<short*>(&h);
}
__device__ __forceinline__ float sigmoidf(float x) {
  return 1.0f / (1.0f + __expf(-x));
}

// ---------------- pool: g[b,c] = mean_s x[b,c,s] -> bf16 --------------------
__global__ __launch_bounds__(256) void pool_kernel(const float* __restrict__ x,
                                                   short* __restrict__ g) {
  __shared__ float sums[784];
  const int tid = threadIdx.x;
  const f32x4* base = (const f32x4*)(x + (size_t)blockIdx.x * (16 * 196));
#pragma unroll
  for (int it = 0; it < 4; ++it) {
    int i = it * 256 + tid;
    if (it < 3 || tid < 16) {
      f32x4 v = base[i];
      sums[i] = v[0] + v[1] + v[2] + v[3];
    }
  }
  __syncthreads();
  if (tid < 16) {
    float s = 0.f;
#pragma unroll
    for (int j = 0; j < 49; ++j) s += sums[tid * 49 + j];
    g[blockIdx.x * 16 + tid] = f2bf(s * (1.0f / 196.0f));
  }
}

// --------- GEMM1 (R11-proven): 1-deep reg prefetch, 16-wave K-split ---------
template<int N, int K, int WAVES, bool OUT_BF16>
__device__ __forceinline__ void gemm_body(const short* __restrict__ A,
                                          const float* __restrict__ B,
                                          const float* __restrict__ bias,
                                          void* __restrict__ outp,
                                          float* __restrict__ red) {
  constexpr int KW = K / WAVES;
  constexpr int NK = KW / 32;
  constexpr int NT = WAVES * 64;
  const int n0  = blockIdx.x * 16;
  const int tid = threadIdx.x;
  const int l   = tid & 63;
  const int wv  = tid >> 6;
  const int kw0 = wv * KW;

  const int ko = (l >> 4) * 8;
  const float* Bp = B + (size_t)(n0 + (l & 15)) * K + kw0 + ko;
  const short* Ap = A + (size_t)(l & 15) * K + kw0 + ko;

  f32x4 acc0 = {}, acc1 = {}, acc2 = {}, acc3 = {};

  f32x4 bc0 = *(const f32x4*)(Bp);
  f32x4 bc1 = *(const f32x4*)(Bp + 4);
  short8 ac0 = *(const short8*)(Ap);
  short8 ac1 = *(const short8*)(Ap + 16 * K);
  short8 ac2 = *(const short8*)(Ap + 32 * K);
  short8 ac3 = *(const short8*)(Ap + 48 * K);

  for (int t = 0; t < NK; ++t) {
    f32x4 bn0 = {}, bn1 = {};
    short8 an0 = {}, an1 = {}, an2 = {}, an3 = {};
    if (t + 1 < NK) {
      const float* bp = Bp + (t + 1) * 32;
      const short* ap = Ap + (t + 1) * 32;
      bn0 = *(const f32x4*)(bp);
      bn1 = *(const f32x4*)(bp + 4);
      an0 = *(const short8*)(ap);
      an1 = *(const short8*)(ap + 16 * K);
      an2 = *(const short8*)(ap + 32 * K);
      an3 = *(const short8*)(ap + 48 * K);
    }
    short8 bb;
    bb[0] = f2bf(bc0[0]); bb[1] = f2bf(bc0[1]); bb[2] = f2bf(bc0[2]); bb[3] = f2bf(bc0[3]);
    bb[4] = f2bf(bc1[0]); bb[5] = f2bf(bc1[1]); bb[6] = f2bf(bc1[2]); bb[7] = f2bf(bc1[3]);
    acc0 = __builtin_amdgcn_mfma_f32_16x16x32_bf16(ac0, bb, acc0, 0, 0, 0);
    acc1 = __builtin_amdgcn_mfma_f32_16x16x32_bf16(ac1, bb, acc1, 0, 0, 0);
    acc2 = __builtin_amdgcn_mfma_f32_16x16x32_bf16(ac2, bb, acc2, 0, 0, 0);
    acc3 = __builtin_amdgcn_mfma_f32_16x16x32_bf16(ac3, bb, acc3, 0, 0, 0);
    bc0 = bn0; bc1 = bn1;
    ac0 = an0; ac1 = an1; ac2 = an2; ac3 = an3;
  }

  {
    float* rw = red + wv * 1024;
    const int mb = (l >> 4) << 2;
    const int nn = l & 15;
#pragma unroll
    for (int r = 0; r < 4; ++r) rw[(0  + mb + r) * 16 + nn] = acc0[r];
#pragma unroll
    for (int r = 0; r < 4; ++r) rw[(16 + mb + r) * 16 + nn] = acc1[r];
#pragma unroll
    for (int r = 0; r < 4; ++r) rw[(32 + mb + r) * 16 + nn] = acc2[r];
#pragma unroll
    for (int r = 0; r < 4; ++r) rw[(48 + mb + r) * 16 + nn] = acc3[r];
  }
  __syncthreads();

#pragma unroll
  for (int i = tid; i < 1024; i += NT) {
    float s = 0.f;
#pragma unroll
    for (int w = 0; w < WAVES; ++w) s += red[w * 1024 + i];
    int m  = i >> 4;
    int nn = n0 + (i & 15);
    s = sigmoidf(s + bias[nn]);
    if constexpr (OUT_BF16) ((short*)outp)[(size_t)m * N + nn] = f2bf(s);
    else                    ((float*)outp)[(size_t)m * N + nn] = s;
  }
}

// GEMM1: 16 waves (1024 threads), 256 blocks -> 16 waves/CU
__global__ __launch_bounds__(1024, 4) void gemm1_kernel(const short* __restrict__ A,
                                                        const float* __restrict__ B,
                                                        const float* __restrict__ bias,
                                                        short* __restrict__ outp) {
  __shared__ float red[16 * 1024];
  gemm_body<4096, 2048, 16, true>(A, B, bias, outp, red);
}

// --------- GEMM2: canonical 2-phase LDS-staged GEMM -------------------------
// 512 blocks x 8 waves; n-tile = 16 w2-rows, K in 8 chunks of 512 f32.
// B chunk (32 KB) staged via global_load_lds width=16 into 2x32KB dbuf,
// XOR-swizzled both-sides (pre-swizzled source, swizzled ds_read — G21).
// A (L2-resident) reg-prefetched one chunk ahead, issued BEFORE stage ops
// so its in-order vmcnt wait never drags the HBM stage. One barrier/chunk.
__global__ __launch_bounds__(512, 4) void gemm2_kernel(const short* __restrict__ A,
                                                       const float* __restrict__ B,
                                                       const float* __restrict__ bias,
                                                       float* __restrict__ outp,
                                                       float* __restrict__ zbuf) {
  constexpr int N = 8192, K = 4096;
  __shared__ float lds[16384];          // 64 KB: 2 x 32 KB B-tile buffers
  const int tid = threadIdx.x;
  const int l   = tid & 63;
  const int wv  = tid >> 6;
  const int n0  = blockIdx.x * 16;

  // zero feat for einsum's atomics (512 blocks x 98 = 50176 floats)
  if (tid < 98) zbuf[blockIdx.x * 98 + tid] = 0.f;

  const char*  gB = (const char*)B + (size_t)n0 * (K * 4);
  const short* Ap = A + (size_t)(l & 15) * K + ((l >> 4) << 3);

  f32x4 acc0 = {}, acc1 = {}, acc2 = {}, acc3 = {};
  short8 a_cur[8], a_nxt[8];

  // ---- helpers (unrolled, static indices) ----
  // stage chunk c into buffer buf: tile = [16 rows][2048 B] row-major linear;
  // thread covers 16B chunk idx=j*512+tid; src byte-in-row = d ^ ((r&7)<<4).
#define G2_STAGE(c_, buf_)                                                     \
  {                                                                            \
    _Pragma("unroll")                                                          \
    for (int j = 0; j < 4; ++j) {                                              \
      int idx = j * 512 + tid;                                                 \
      int r   = idx >> 7;                                                      \
      int d   = (idx & 127) << 4;                                              \
      int s   = d ^ ((r & 7) << 4);                                            \
      const char* src = gB + (size_t)r * (K * 4) + (size_t)(c_) * 2048 + s;    \
      char* dst = (char*)lds + (buf_) * 32768 +                                \
                  (size_t)(j * 512 + (tid & ~63)) * 16;                        \
      __builtin_amdgcn_global_load_lds((as1_u32*)src, (as3_u32*)dst, 16, 0, 0);\
    }                                                                          \
  }
#define G2_LOADA(c_, ar_)                                                      \
  {                                                                            \
    const short* ap = Ap + (c_) * 512 + wv * 64;                               \
    _Pragma("unroll")                                                          \
    for (int t = 0; t < 2; ++t) {                                              \
      _Pragma("unroll")                                                        \
      for (int f = 0; f < 4; ++f)                                              \
        ar_[t * 4 + f] = *(const short8*)(ap + t * 32 + (size_t)f * 16 * K);   \
    }                                                                          \
  }

  // prologue
  G2_LOADA(0, a_cur);
  G2_STAGE(0, 0);
  __syncthreads();

  const int row = l & 15;
  const int swz = (row & 7) << 4;
  const int rb  = row * 2048;
  const int ko4 = ((l >> 4) << 3) << 2;   // byte offset of lane's k-slice

  for (int c = 0; c < 8; ++c) {
    if (c < 7) {
      G2_LOADA(c + 1, a_nxt);            // L2 loads first (in-order vmcnt)
      G2_STAGE(c + 1, (c + 1) & 1);      // then HBM stage
    }
    const char* bufc = (const char*)lds + (c & 1) * 32768;
#pragma unroll
    for (int t = 0; t < 2; ++t) {
      int kb = (wv << 8) + (t << 7) + ko4;      // (wv*64 + t*32 + ko8)*4 bytes
      f32x4 b0 = *(const f32x4*)(bufc + rb + ((kb)      ^ swz));
      f32x4 b1 = *(const f32x4*)(bufc + rb + ((kb + 16) ^ swz));
      short8 bb;
      bb[0] = f2bf(b0[0]); bb[1] = f2bf(b0[1]); bb[2] = f2bf(b0[2]); bb[3] = f2bf(b0[3]);
      bb[4] = f2bf(b1[0]); bb[5] = f2bf(b1[1]); bb[6] = f2bf(b1[2]); bb[7] = f2bf(b1[3]);
      acc0 = __builtin_amdgcn_mfma_f32_16x16x32_bf16(a_cur[t * 4 + 0], bb, acc0, 0, 0, 0);
      acc1 = __builtin_amdgcn_mfma_f32_16x16x32_bf16(a_cur[t * 4 + 1], bb, acc1, 0, 0, 0);
      acc2 = __builtin_amdgcn_mfma_f32_16x16x32_bf16(a_cur[t * 4 + 2], bb, acc2, 0, 0, 0);
      acc3 = __builtin_amdgcn_mfma_f32_16x16x32_bf16(a_cur[t * 4 + 3], bb, acc3, 0, 0, 0);
    }
    __syncthreads();                     // drains vmcnt: stage(c+1)+A(c+1) done
    if (c < 7) {
#pragma unroll
      for (int i = 0; i < 8; ++i) a_cur[i] = a_nxt[i];
    }
  }

  // epilogue: reuse LDS (first 32 KB) to reduce 8 wave-partials
  float* red = lds;
  {
    float* rw = red + wv * 1024;
    const int mb = (l >> 4) << 2;
    const int nn = l & 15;
#pragma unroll
    for (int r = 0; r < 4; ++r) rw[(0  + mb + r) * 16 + nn] = acc0[r];
#pragma unroll
    for (int r = 0; r < 4; ++r) rw[(16 + mb + r) * 16 + nn] = acc1[r];
#pragma unroll
    for (int r = 0; r < 4; ++r) rw[(32 + mb + r) * 16 + nn] = acc2[r];
#pragma unroll
    for (int r = 0; r < 4; ++r) rw[(48 + mb + r) * 16 + nn] = acc3[r];
  }
  __syncthreads();
#pragma unroll
  for (int i = tid; i < 1024; i += 512) {
    float s = 0.f;
#pragma unroll
    for (int w = 0; w < 8; ++w) s += red[w * 1024 + i];
    int m  = i >> 4;
    int nn = n0 + (i & 15);
    outp[(size_t)m * N + nn] = sigmoidf(s + bias[nn]);
  }
#undef G2_STAGE
#undef G2_LOADA
}

// --------- einsum: feat[b,p,s] += (1/C) sum_{c in chunk} w[b,p,c] x[b,c,s] --
__global__ __launch_bounds__(256) void einsum_kernel(const float* __restrict__ x,
                                                     const float* __restrict__ wg,
                                                     float* __restrict__ feat) {
  const int b   = blockIdx.x >> 4;
  const int cc  = blockIdx.x & 15;
  const int tid = threadIdx.x;
  if (tid >= 196) return;
  const float* wp = wg + (size_t)b * 8192 + cc * 128;
  const float* xp = x + (size_t)b * 2048 * 196 + (size_t)cc * 128 * 196 + tid;
  float a0 = 0.f, a1 = 0.f, a2 = 0.f, a3 = 0.f;
#pragma unroll 8
  for (int c = 0; c < 128; ++c) {
    float xv = xp[(size_t)c * 196];
    a0 = __builtin_fmaf(wp[c],        xv, a0);
    a1 = __builtin_fmaf(wp[2048 + c], xv, a1);
    a2 = __builtin_fmaf(wp[4096 + c], xv, a2);
    a3 = __builtin_fmaf(wp[6144 + c], xv, a3);
  }
  const float invC = 1.0f / 2048.0f;
  atomicAdd(feat + (b * 4 + 0) * 196 + tid, a0 * invC);
  atomicAdd(feat + (b * 4 + 1) * 196 + tid, a1 * invC);
  atomicAdd(feat + (b * 4 + 2) * 196 + tid, a2 * invC);
  atomicAdd(feat + (b * 4 + 3) * 196 + tid, a3 * invC);
}

extern "C" void kernel_launch(void* const* d_in, const int* in_sizes, int n_in,
                              void* d_out, int out_size, void* d_ws, size_t ws_size,
                              hipStream_t stream) {
  const float* x  = (const float*)d_in[0];   // [64,2048,14,14]
  const float* w1 = (const float*)d_in[1];   // [4096,2048]
  const float* b1 = (const float*)d_in[2];   // [4096]
  const float* w2 = (const float*)d_in[3];   // [8192,4096]
  const float* b2 = (const float*)d_in[4];   // [8192]
  float* out = (float*)d_out;

  short* g_bf = (short*)d_ws;                // 64*2048 bf16 (256 KB)
  short* h_bf = g_bf + 64 * 2048;            // 64*4096 bf16 (512 KB)

  float* wout = out;                         // [64, 8192] == [B,P,C] flat
  float* feat = out + 524288;                // [64, 4, 196]

  // 1) pool -> g (bf16): 8192 blocks x 16 rows
  pool_kernel<<<8192, 256, 0, stream>>>(x, g_bf);

  // 2) GEMM1: h = sigmoid(g @ w1^T + b1), bf16 out (256 blocks x 16 waves)
  gemm1_kernel<<<4096 / 16, 1024, 0, stream>>>(g_bf, w1, b1, h_bf);

  // 3) GEMM2: LDS-staged, w = sigmoid(h @ w2^T + b2); also zeroes feat
  gemm2_kernel<<<512, 512, 0, stream>>>(h_bf, w2, b2, wout, feat);

  // 4) einsum -> feat (atomic accumulate over 16 c-chunks)
  einsum_kernel<<<64 * 16, 256, 0, stream>>>(x, wout, feat);
}